// Round 5
// baseline (229.200 us; speedup 1.0000x reference)
//
#include <hip/hip_runtime.h>
#include <math.h>

#define NN 10000
#define NE 320000
#define DD 256
#define KSEL 8000
#define KK 512

typedef unsigned int uint;
typedef unsigned short ushort;
typedef __attribute__((ext_vector_type(8))) short short8;   // 8 bf16 (4 VGPR)
typedef __attribute__((ext_vector_type(4))) float f32x4;
typedef __attribute__((ext_vector_type(4))) ushort us4;
typedef __attribute__((ext_vector_type(8))) ushort us8;

__device__ __forceinline__ void atomAddF(float* p, float v) {
    unsafeAtomicAdd(p, v);   // HW global_atomic_add_f32
}

__device__ __forceinline__ uint encodeF(float f) {
    uint u = __float_as_uint(f);
    return (u & 0x80000000u) ? ~u : (u | 0x80000000u);
}

__device__ __forceinline__ ushort f2bf(float f) {   // round-to-nearest-even
    uint u = __float_as_uint(f);
    u += 0x7FFFu + ((u >> 16) & 1u);
    return (ushort)(u >> 16);
}

// ---------------- 1. prep: cast_h + cast_W + count_deg (fused) ------------
#define QH (NN * 64)          // h cast quads
#define QW (KK * DD)          // W cast elems
__global__ __launch_bounds__(256) void prep(
    const float* __restrict__ h, const float* __restrict__ W_l,
    const float* __restrict__ W_r, const int* __restrict__ ei,
    ushort* __restrict__ Ab, ushort* __restrict__ Wt,
    int* __restrict__ degi) {
    int id = blockIdx.x * 256 + threadIdx.x;
    if (id < QH) {                       // ---- cast h -> A cols 256..511
        int node = id >> 6, seg = (id & 63) * 4;
        float4 v = *(const float4*)(h + (size_t)node * DD + seg);
        us4 o;
        o[0] = f2bf(v.x); o[1] = f2bf(v.y); o[2] = f2bf(v.z); o[3] = f2bf(v.w);
        *(us4*)(Ab + (size_t)node * KK + 256 + seg) = o;
    } else if (id < QH + QW) {           // ---- cast+transpose W -> Wt[256][512]
        int idx = id - QH;
        int k = idx >> 8, n = idx & 255;
        float v = (k < 256) ? W_l[(size_t)k * DD + n]
                            : W_r[(size_t)(k - 256) * DD + n];
        Wt[(size_t)n * KK + k] = f2bf(v);
    } else if (id < QH + QW + NE) {      // ---- degree histogram
        int e = id - QH - QW;
        atomicAdd(&degi[ei[NE + e]], 1);
    }
}

// ---------------- 2. single-block prefix scan -> start/cursor/invdeg ------
__global__ __launch_bounds__(1024) void scan_start(
    const int* __restrict__ degi, int* __restrict__ start,
    int* __restrict__ cursor, float* __restrict__ invdeg) {
    __shared__ int partial[1024];
    const int t  = threadIdx.x;
    const int CH = (NN + 1023) / 1024;   // 10
    const int base = t * CH;
    int sum = 0;
#pragma unroll
    for (int i = 0; i < CH; i++) {
        int idx = base + i;
        if (idx < NN) sum += degi[idx];
    }
    partial[t] = sum;
    __syncthreads();
    for (int off = 1; off < 1024; off <<= 1) {
        int add = (t >= off) ? partial[t - off] : 0;
        __syncthreads();
        partial[t] += add;
        __syncthreads();
    }
    int run = partial[t] - sum;
#pragma unroll
    for (int i = 0; i < CH; i++) {
        int idx = base + i;
        if (idx < NN) {
            start[idx]  = run;
            cursor[idx] = run;
            int d = degi[idx];
            invdeg[idx] = 1.0f / fmaxf((float)d, 1.0f);
            run += d;
        }
    }
    if (t == 1023) start[NN] = NE;
}

// ---------------- 3. fill CSR (group edges by dst) ------------------------
__global__ __launch_bounds__(256) void fill_csr(
    const int* __restrict__ ei, int* __restrict__ cursor,
    int* __restrict__ csr) {
    int e = blockIdx.x * 256 + threadIdx.x;
    if (e >= NE) return;
    int pos = atomicAdd(&cursor[ei[NE + e]], 1);
    csr[pos] = ei[e];
}

// ---------------- 4. gather-aggregate (bf16 reads) -> bf16 mean -----------
__global__ __launch_bounds__(256) void gather_mean(
    ushort* __restrict__ Ab, const int* __restrict__ csr,
    const int* __restrict__ start, const float* __restrict__ invdeg) {
    int node = blockIdx.x * 4 + (threadIdx.x >> 6);
    int lane = threadIdx.x & 63;
    if (node >= NN) return;
    int s = start[node], e = start[node + 1];
    const ushort* hb = Ab + 256 + lane * 4;            // h half of A
    float a0 = 0.f, a1 = 0.f, a2 = 0.f, a3 = 0.f;
    float b0 = 0.f, b1 = 0.f, b2 = 0.f, b3 = 0.f;
    int j = s;
    for (; j + 2 <= e; j += 2) {
        int s0 = csr[j], s1 = csr[j + 1];
        uint2 v0 = *(const uint2*)(hb + (size_t)s0 * KK);
        uint2 v1 = *(const uint2*)(hb + (size_t)s1 * KK);
        a0 += __uint_as_float(v0.x << 16);
        a1 += __uint_as_float(v0.x & 0xFFFF0000u);
        a2 += __uint_as_float(v0.y << 16);
        a3 += __uint_as_float(v0.y & 0xFFFF0000u);
        b0 += __uint_as_float(v1.x << 16);
        b1 += __uint_as_float(v1.x & 0xFFFF0000u);
        b2 += __uint_as_float(v1.y << 16);
        b3 += __uint_as_float(v1.y & 0xFFFF0000u);
    }
    for (; j < e; j++) {
        uint2 v0 = *(const uint2*)(hb + (size_t)csr[j] * KK);
        a0 += __uint_as_float(v0.x << 16);
        a1 += __uint_as_float(v0.x & 0xFFFF0000u);
        a2 += __uint_as_float(v0.y << 16);
        a3 += __uint_as_float(v0.y & 0xFFFF0000u);
    }
    float id = invdeg[node];
    us4 m;
    m[0] = f2bf((a0 + b0) * id);
    m[1] = f2bf((a1 + b1) * id);
    m[2] = f2bf((a2 + b2) * id);
    m[3] = f2bf((a3 + b3) * id);
    *(us4*)(Ab + (size_t)node * KK + lane * 4) = m;    // mean half of A
}

// ---------------- 5. MFMA GEMM: x = relu(A@Wt^T + b_l), fused y/c/r -------
__global__ __launch_bounds__(256) void gemm_x(
    const ushort* __restrict__ Ab, const ushort* __restrict__ Wt,
    const float* __restrict__ b_l,
    const float* __restrict__ W_rel, const float* __restrict__ W_gate,
    const float* __restrict__ W_root,
    float* __restrict__ xout, float* __restrict__ y,
    float* __restrict__ cvec, float* __restrict__ rvec) {
    __shared__ ushort Asm[2][32][40];    // +8 pad: 2-way banks max
    __shared__ ushort Bsm[2][256][40];
    const int t    = threadIdx.x;
    const int row0 = blockIdx.x * 32;
    const int wid  = t >> 6, lane = t & 63;
    const int l15  = lane & 15, g = lane >> 4;

    f32x4 acc[2][4];
#pragma unroll
    for (int fi = 0; fi < 2; fi++)
#pragma unroll
        for (int fj = 0; fj < 4; fj++) acc[fi][fj] = (f32x4)0.f;

    const int  arow = t >> 3, akseg = (t & 7) * 4;
    const bool aok  = (row0 + arow) < NN;
    const ushort* aptr = Ab + (size_t)(row0 + arow) * KK + akseg;
    const ushort* bptr = Wt + (size_t)t * KK;

    us4 areg = {0, 0, 0, 0};
    us8 breg[4];
    if (aok) areg = *(const us4*)(aptr);
#pragma unroll
    for (int jj = 0; jj < 4; jj++) breg[jj] = *(const us8*)(bptr + jj * 8);
    *(us4*)&Asm[0][arow][akseg] = areg;
#pragma unroll
    for (int jj = 0; jj < 4; jj++) *(us8*)&Bsm[0][t][jj * 8] = breg[jj];
    __syncthreads();

    for (int ks = 0; ks < 16; ++ks) {
        const int cur = ks & 1;
        if (ks < 15) {
            const int k0 = (ks + 1) * 32;
            if (aok) areg = *(const us4*)(aptr + k0);
#pragma unroll
            for (int jj = 0; jj < 4; jj++) breg[jj] = *(const us8*)(bptr + k0 + jj * 8);
        }
        short8 af0 = *(const short8*)&Asm[cur][l15][g * 8];
        short8 af1 = *(const short8*)&Asm[cur][16 + l15][g * 8];
#pragma unroll
        for (int fj = 0; fj < 4; fj++) {
            short8 bf = *(const short8*)&Bsm[cur][wid * 64 + fj * 16 + l15][g * 8];
            acc[0][fj] = __builtin_amdgcn_mfma_f32_16x16x32_bf16(af0, bf, acc[0][fj], 0, 0, 0);
            acc[1][fj] = __builtin_amdgcn_mfma_f32_16x16x32_bf16(af1, bf, acc[1][fj], 0, 0, 0);
        }
        if (ks < 15) {
            const int nb = cur ^ 1;
            *(us4*)&Asm[nb][arow][akseg] = areg;
#pragma unroll
            for (int jj = 0; jj < 4; jj++) *(us8*)&Bsm[nb][t][jj * 8] = breg[jj];
        }
        __syncthreads();
    }

    const int wcol0 = wid * 64;
    float bl[4], wl[4], wg[4], wo[4];
#pragma unroll
    for (int fj = 0; fj < 4; fj++) {
        int col = wcol0 + fj * 16 + l15;
        bl[fj] = b_l[col]; wl[fj] = W_rel[col];
        wg[fj] = W_gate[col]; wo[fj] = W_root[col];
    }
#pragma unroll
    for (int fi = 0; fi < 2; fi++) {
#pragma unroll
        for (int r = 0; r < 4; r++) {
            int row = row0 + fi * 16 + g * 4 + r;
            if (row >= NN) continue;
            float py = 0.f, pc = 0.f, pr = 0.f;
#pragma unroll
            for (int fj = 0; fj < 4; fj++) {
                float v = fmaxf(acc[fi][fj][r] + bl[fj], 0.f);
                xout[(size_t)row * DD + wcol0 + fj * 16 + l15] = v;
                py = fmaf(v, wl[fj], py);
                pc = fmaf(v, wg[fj], pc);
                pr = fmaf(v, wo[fj], pr);
            }
#pragma unroll
            for (int off = 1; off < 16; off <<= 1) {
                py += __shfl_xor(py, off);
                pc += __shfl_xor(pc, off);
                pr += __shfl_xor(pr, off);
            }
            if (l15 == 0) {
                atomAddF(y + row, py);
                atomAddF(cvec + row, pc);
                atomAddF(rvec + row, pr);
            }
        }
    }
}

// ---------------- 6. gather y along CSR, score = tanh(.), sortable key ----
__global__ __launch_bounds__(256) void gather_score(
    const float* __restrict__ y, const float* __restrict__ r,
    const float* __restrict__ b_rel, const int* __restrict__ csr,
    const int* __restrict__ start,
    float* __restrict__ score, uint* __restrict__ key) {
    int gt   = blockIdx.x * 256 + threadIdx.x;
    int node = gt >> 6, lane = gt & 63;
    if (node >= NN) return;
    int s = start[node], e = start[node + 1];
    float acc = 0.f;
    for (int j = s + lane; j < e; j += 64) acc += y[csr[j]];
    for (int o = 32; o; o >>= 1) acc += __shfl_xor(acc, o);
    if (lane == 0) {
        float sc = tanhf(acc + b_rel[0] + r[node]);
        score[node] = sc;
        key[node]   = encodeF(sc);
    }
}

// ---------------- 7. radix select + max-logit + dense weights + denom -----
__global__ __launch_bounds__(1024) void radix_select(
    const uint* __restrict__ key, const float* __restrict__ score,
    const float* __restrict__ cvec,
    float* __restrict__ wsc, float* __restrict__ denom) {
    __shared__ uint  hist[256];
    __shared__ uint  ssum[256];
    __shared__ uint  sh_prefix, sh_need;
    __shared__ float wred[16];
    __shared__ uint  tick_s;
    const int t = threadIdx.x;
    uint prefix = 0, pmask = 0, need = KSEL;
    for (int shift = 24; shift >= 0; shift -= 8) {
        if (t < 256) hist[t] = 0;
        __syncthreads();
        for (int i = t; i < NN; i += 1024) {
            uint k = key[i];
            if ((k & pmask) == prefix) atomicAdd(&hist[(k >> shift) & 255], 1u);
        }
        __syncthreads();
        if (t < 256) ssum[t] = hist[t];
        __syncthreads();
        for (int off = 1; off < 256; off <<= 1) {   // parallel suffix sum
            uint add = 0;
            if (t < 256 && t + off < 256) add = ssum[t + off];
            __syncthreads();
            if (t < 256) ssum[t] += add;
            __syncthreads();
        }
        if (t < 256) {
            uint hi = ssum[t];
            uint lo = (t < 255) ? ssum[t + 1] : 0u;
            if (need <= hi && need > lo) {
                sh_prefix = prefix | ((uint)t << shift);
                sh_need   = need - lo;
            }
        }
        __syncthreads();
        prefix = sh_prefix;
        need   = sh_need;
        pmask |= (0xFFu << shift);
        __syncthreads();
    }
    const uint T      = prefix;
    const uint needEq = need;
    // ---- pass A: max logit over superset {key >= T} ----
    float v = -INFINITY;
    for (int i = t; i < NN; i += 1024)
        if (key[i] >= T) v = fmaxf(v, score[i] * cvec[i]);
    for (int o = 32; o; o >>= 1) v = fmaxf(v, __shfl_xor(v, o));
    if ((t & 63) == 0) wred[t >> 6] = v;
    if (t == 0) tick_s = 0;
    __syncthreads();
    float m = wred[0];
#pragma unroll
    for (int w = 1; w < 16; w++) m = fmaxf(m, wred[w]);
    __syncthreads();          // everyone has m before wred is reused
    // ---- pass B: dense weights + denom ----
    float dsum = 0.f;
    for (int i = t; i < NN; i += 1024) {
        uint k = key[i];
        bool selm = (k > T);
        if (k == T) selm = (atomicAdd(&tick_s, 1u) < needEq);
        float wv = 0.f;
        if (selm) {
            float s = score[i];
            float w = expf(s * cvec[i] - m);
            wv   = w * s;
            dsum += w;
        }
        wsc[i] = wv;
    }
    for (int o = 32; o; o >>= 1) dsum += __shfl_xor(dsum, o);
    if ((t & 63) == 0) wred[t >> 6] = dsum;
    __syncthreads();
    if (t == 0) {
        float d = 0.f;
#pragma unroll
        for (int w = 0; w < 16; w++) d += wred[w];
        denom[0] = d;
    }
}

// ---------------- 8. dense weighted row-sum: numer = sum wsc[i]*x[i] ------
// 625 waves x 16 rows, unrolled x4 -> 4 (w, 1KB-row) pairs in flight.
__global__ __launch_bounds__(256) void reduce_rows(
    const float* __restrict__ x, const float* __restrict__ wsc,
    float* __restrict__ numer) {
    int wave = blockIdx.x * 4 + (threadIdx.x >> 6);
    int lane = threadIdx.x & 63;
    int row0 = wave * 16;
    if (row0 >= NN) return;
    const float* xp = x + lane * 4;
    float4 acc = make_float4(0.f, 0.f, 0.f, 0.f);
#pragma unroll
    for (int rb = 0; rb < 16; rb += 4) {
        int r0 = row0 + rb;
        float w0 = wsc[r0 + 0], w1 = wsc[r0 + 1];
        float w2 = wsc[r0 + 2], w3 = wsc[r0 + 3];
        float4 v0 = *(const float4*)(xp + (size_t)(r0 + 0) * DD);
        float4 v1 = *(const float4*)(xp + (size_t)(r0 + 1) * DD);
        float4 v2 = *(const float4*)(xp + (size_t)(r0 + 2) * DD);
        float4 v3 = *(const float4*)(xp + (size_t)(r0 + 3) * DD);
        acc.x = fmaf(w0, v0.x, fmaf(w1, v1.x, fmaf(w2, v2.x, fmaf(w3, v3.x, acc.x))));
        acc.y = fmaf(w0, v0.y, fmaf(w1, v1.y, fmaf(w2, v2.y, fmaf(w3, v3.y, acc.y))));
        acc.z = fmaf(w0, v0.z, fmaf(w1, v1.z, fmaf(w2, v2.z, fmaf(w3, v3.z, acc.z))));
        acc.w = fmaf(w0, v0.w, fmaf(w1, v1.w, fmaf(w2, v2.w, fmaf(w3, v3.w, acc.w))));
    }
    atomAddF(numer + lane * 4 + 0, acc.x);
    atomAddF(numer + lane * 4 + 1, acc.y);
    atomAddF(numer + lane * 4 + 2, acc.z);
    atomAddF(numer + lane * 4 + 3, acc.w);
}

// ---------------- 9. finalize ---------------------------------------------
__global__ __launch_bounds__(256) void finalize(
    const float* __restrict__ numer, const float* __restrict__ denom,
    float* __restrict__ out) {
    int i  = threadIdx.x;
    out[i] = numer[i] / denom[0];
}

extern "C" void kernel_launch(void* const* d_in, const int* in_sizes, int n_in,
                              void* d_out, int out_size, void* d_ws, size_t ws_size,
                              hipStream_t stream) {
    const float* h      = (const float*)d_in[0];
    const int*   ei     = (const int*)d_in[1];
    const float* W_l    = (const float*)d_in[2];
    const float* b_l    = (const float*)d_in[3];
    const float* W_r    = (const float*)d_in[4];
    const float* W_rel  = (const float*)d_in[5];
    const float* b_rel  = (const float*)d_in[6];
    const float* W_root = (const float*)d_in[7];
    const float* W_gate = (const float*)d_in[8];
    // b_gate (d_in[9]) cancels in softmax
    float* out = (float*)d_out;

    // ---- workspace layout ----
    ushort* Ab    = (ushort*)d_ws;                    // [NN][512] bf16: [mean|h]
    float*  xbuf  = (float*)(Ab + (size_t)NN * KK);   // N*D f32
    ushort* Wt    = (ushort*)(xbuf + (size_t)NN * DD);// [256][512] bf16
    int*    csr   = (int*)(Wt + (size_t)DD * KK);     // E
    int*    start = csr + NE;                         // N+1
    int*    cursor= start + NN + 1;                   // N
    float*  invdeg= (float*)(cursor + NN);            // N
    float*  score = invdeg + NN;                      // N
    uint*   key   = (uint*)(score + NN);              // N
    float*  wsc   = (float*)(key + NN);               // N (fully written)
    float*  denom = wsc + NN;                         // 1 (written directly)
    // ---- zero-initialized tail (one small memset) ----
    int*    degi  = (int*)(denom + 1);                // N
    float*  y     = (float*)(degi + NN);              // N
    float*  cbuf  = y + NN;                           // N
    float*  rbuf  = cbuf + NN;                        // N
    float*  numer = rbuf + NN;                        // D
    size_t zbytes = (size_t)((char*)(numer + DD) - (char*)degi);

    hipMemsetAsync(degi, 0, zbytes, stream);

    prep        <<<(QH + QW + NE + 255) / 256, 256, 0, stream>>>(h, W_l, W_r, ei,
                                                                 Ab, Wt, degi);
    scan_start  <<<1, 1024, 0, stream>>>(degi, start, cursor, invdeg);
    fill_csr    <<<(NE + 255) / 256, 256, 0, stream>>>(ei, cursor, csr);
    gather_mean <<<(NN + 3) / 4, 256, 0, stream>>>(Ab, csr, start, invdeg);
    gemm_x      <<<(NN + 31) / 32, 256, 0, stream>>>(Ab, Wt, b_l,
                                                     W_rel, W_gate, W_root,
                                                     xbuf, y, cbuf, rbuf);
    gather_score<<<(NN * 64 + 255) / 256, 256, 0, stream>>>(y, rbuf, b_rel, csr,
                                                            start, score, key);
    radix_select<<<1, 1024, 0, stream>>>(key, score, cbuf, wsc, denom);
    reduce_rows <<<157, 256, 0, stream>>>(xbuf, wsc, numer);
    finalize    <<<1, 256, 0, stream>>>(numer, denom, out);
    (void)n_in; (void)in_sizes; (void)out_size; (void)ws_size;
}

// Round 6
// 180.277 us; speedup vs baseline: 1.2714x; 1.2714x over previous
//
#include <hip/hip_runtime.h>
#include <math.h>

#define NN 10000
#define NE 320000
#define DD 256
#define KSEL 8000
#define KK 512
#define NPART 157          // reduce_rows grid

typedef unsigned int uint;
typedef unsigned short ushort;
typedef __attribute__((ext_vector_type(8))) short short8;   // 8 bf16 (4 VGPR)
typedef __attribute__((ext_vector_type(4))) float f32x4;
typedef __attribute__((ext_vector_type(4))) ushort us4;
typedef __attribute__((ext_vector_type(8))) ushort us8;

__device__ __forceinline__ void atomAddF(float* p, float v) {
    unsafeAtomicAdd(p, v);   // HW global_atomic_add_f32
}

__device__ __forceinline__ uint encodeF(float f) {
    uint u = __float_as_uint(f);
    return (u & 0x80000000u) ? ~u : (u | 0x80000000u);
}

__device__ __forceinline__ ushort f2bf(float f) {   // round-to-nearest-even
    uint u = __float_as_uint(f);
    u += 0x7FFFu + ((u >> 16) & 1u);
    return (ushort)(u >> 16);
}

// ---------------- 1. prep: cast_h + cast_W + count_deg (fused) ------------
#define QH (NN * 64)          // h cast quads
#define QW (KK * DD)          // W cast elems
__global__ __launch_bounds__(256) void prep(
    const float* __restrict__ h, const float* __restrict__ W_l,
    const float* __restrict__ W_r, const int* __restrict__ ei,
    ushort* __restrict__ Ab, ushort* __restrict__ Wt,
    int* __restrict__ degi) {
    int id = blockIdx.x * 256 + threadIdx.x;
    if (id < QH) {                       // ---- cast h -> A cols 256..511
        int node = id >> 6, seg = (id & 63) * 4;
        float4 v = *(const float4*)(h + (size_t)node * DD + seg);
        us4 o;
        o[0] = f2bf(v.x); o[1] = f2bf(v.y); o[2] = f2bf(v.z); o[3] = f2bf(v.w);
        *(us4*)(Ab + (size_t)node * KK + 256 + seg) = o;
    } else if (id < QH + QW) {           // ---- cast+transpose W -> Wt[256][512]
        int idx = id - QH;
        int k = idx >> 8, n = idx & 255;
        float v = (k < 256) ? W_l[(size_t)k * DD + n]
                            : W_r[(size_t)(k - 256) * DD + n];
        Wt[(size_t)n * KK + k] = f2bf(v);
    } else if (id < QH + QW + NE) {      // ---- degree histogram
        int e = id - QH - QW;
        atomicAdd(&degi[ei[NE + e]], 1);
    }
}

// ---------------- 2. single-block prefix scan -> start/cursor/invdeg ------
__global__ __launch_bounds__(1024) void scan_start(
    const int* __restrict__ degi, int* __restrict__ start,
    int* __restrict__ cursor, float* __restrict__ invdeg) {
    __shared__ int partial[1024];
    const int t  = threadIdx.x;
    const int CH = (NN + 1023) / 1024;   // 10
    const int base = t * CH;
    int sum = 0;
#pragma unroll
    for (int i = 0; i < CH; i++) {
        int idx = base + i;
        if (idx < NN) sum += degi[idx];
    }
    partial[t] = sum;
    __syncthreads();
    for (int off = 1; off < 1024; off <<= 1) {
        int add = (t >= off) ? partial[t - off] : 0;
        __syncthreads();
        partial[t] += add;
        __syncthreads();
    }
    int run = partial[t] - sum;
#pragma unroll
    for (int i = 0; i < CH; i++) {
        int idx = base + i;
        if (idx < NN) {
            start[idx]  = run;
            cursor[idx] = run;
            int d = degi[idx];
            invdeg[idx] = 1.0f / fmaxf((float)d, 1.0f);
            run += d;
        }
    }
    if (t == 1023) start[NN] = NE;
}

// ---------------- 3. fill CSR (group edges by dst) ------------------------
__global__ __launch_bounds__(256) void fill_csr(
    const int* __restrict__ ei, int* __restrict__ cursor,
    int* __restrict__ csr) {
    int e = blockIdx.x * 256 + threadIdx.x;
    if (e >= NE) return;
    int pos = atomicAdd(&cursor[ei[NE + e]], 1);
    csr[pos] = ei[e];
}

// ---------------- 4. gather-aggregate (bf16 reads) -> bf16 mean -----------
__global__ __launch_bounds__(256) void gather_mean(
    ushort* __restrict__ Ab, const int* __restrict__ csr,
    const int* __restrict__ start, const float* __restrict__ invdeg) {
    int node = blockIdx.x * 4 + (threadIdx.x >> 6);
    int lane = threadIdx.x & 63;
    if (node >= NN) return;
    int s = start[node], e = start[node + 1];
    const ushort* hb = Ab + 256 + lane * 4;            // h half of A
    float a0 = 0.f, a1 = 0.f, a2 = 0.f, a3 = 0.f;
    float b0 = 0.f, b1 = 0.f, b2 = 0.f, b3 = 0.f;
    int j = s;
    for (; j + 2 <= e; j += 2) {
        int s0 = csr[j], s1 = csr[j + 1];
        uint2 v0 = *(const uint2*)(hb + (size_t)s0 * KK);
        uint2 v1 = *(const uint2*)(hb + (size_t)s1 * KK);
        a0 += __uint_as_float(v0.x << 16);
        a1 += __uint_as_float(v0.x & 0xFFFF0000u);
        a2 += __uint_as_float(v0.y << 16);
        a3 += __uint_as_float(v0.y & 0xFFFF0000u);
        b0 += __uint_as_float(v1.x << 16);
        b1 += __uint_as_float(v1.x & 0xFFFF0000u);
        b2 += __uint_as_float(v1.y << 16);
        b3 += __uint_as_float(v1.y & 0xFFFF0000u);
    }
    for (; j < e; j++) {
        uint2 v0 = *(const uint2*)(hb + (size_t)csr[j] * KK);
        a0 += __uint_as_float(v0.x << 16);
        a1 += __uint_as_float(v0.x & 0xFFFF0000u);
        a2 += __uint_as_float(v0.y << 16);
        a3 += __uint_as_float(v0.y & 0xFFFF0000u);
    }
    float id = invdeg[node];
    us4 m;
    m[0] = f2bf((a0 + b0) * id);
    m[1] = f2bf((a1 + b1) * id);
    m[2] = f2bf((a2 + b2) * id);
    m[3] = f2bf((a3 + b3) * id);
    *(us4*)(Ab + (size_t)node * KK + lane * 4) = m;    // mean half of A
}

// ---------------- 5. MFMA GEMM: x = relu(A@Wt^T + b_l), fused y/c/r -------
__global__ __launch_bounds__(256) void gemm_x(
    const ushort* __restrict__ Ab, const ushort* __restrict__ Wt,
    const float* __restrict__ b_l,
    const float* __restrict__ W_rel, const float* __restrict__ W_gate,
    const float* __restrict__ W_root,
    float* __restrict__ xout, float* __restrict__ y,
    float* __restrict__ cvec, float* __restrict__ rvec) {
    __shared__ ushort Asm[2][32][40];    // +8 pad: 2-way banks max
    __shared__ ushort Bsm[2][256][40];
    const int t    = threadIdx.x;
    const int row0 = blockIdx.x * 32;
    const int wid  = t >> 6, lane = t & 63;
    const int l15  = lane & 15, g = lane >> 4;

    f32x4 acc[2][4];
#pragma unroll
    for (int fi = 0; fi < 2; fi++)
#pragma unroll
        for (int fj = 0; fj < 4; fj++) acc[fi][fj] = (f32x4)0.f;

    const int  arow = t >> 3, akseg = (t & 7) * 4;
    const bool aok  = (row0 + arow) < NN;
    const ushort* aptr = Ab + (size_t)(row0 + arow) * KK + akseg;
    const ushort* bptr = Wt + (size_t)t * KK;

    us4 areg = {0, 0, 0, 0};
    us8 breg[4];
    if (aok) areg = *(const us4*)(aptr);
#pragma unroll
    for (int jj = 0; jj < 4; jj++) breg[jj] = *(const us8*)(bptr + jj * 8);
    *(us4*)&Asm[0][arow][akseg] = areg;
#pragma unroll
    for (int jj = 0; jj < 4; jj++) *(us8*)&Bsm[0][t][jj * 8] = breg[jj];
    __syncthreads();

    for (int ks = 0; ks < 16; ++ks) {
        const int cur = ks & 1;
        if (ks < 15) {
            const int k0 = (ks + 1) * 32;
            if (aok) areg = *(const us4*)(aptr + k0);
#pragma unroll
            for (int jj = 0; jj < 4; jj++) breg[jj] = *(const us8*)(bptr + k0 + jj * 8);
        }
        short8 af0 = *(const short8*)&Asm[cur][l15][g * 8];
        short8 af1 = *(const short8*)&Asm[cur][16 + l15][g * 8];
#pragma unroll
        for (int fj = 0; fj < 4; fj++) {
            short8 bf = *(const short8*)&Bsm[cur][wid * 64 + fj * 16 + l15][g * 8];
            acc[0][fj] = __builtin_amdgcn_mfma_f32_16x16x32_bf16(af0, bf, acc[0][fj], 0, 0, 0);
            acc[1][fj] = __builtin_amdgcn_mfma_f32_16x16x32_bf16(af1, bf, acc[1][fj], 0, 0, 0);
        }
        if (ks < 15) {
            const int nb = cur ^ 1;
            *(us4*)&Asm[nb][arow][akseg] = areg;
#pragma unroll
            for (int jj = 0; jj < 4; jj++) *(us8*)&Bsm[nb][t][jj * 8] = breg[jj];
        }
        __syncthreads();
    }

    const int wcol0 = wid * 64;
    float bl[4], wl[4], wg[4], wo[4];
#pragma unroll
    for (int fj = 0; fj < 4; fj++) {
        int col = wcol0 + fj * 16 + l15;
        bl[fj] = b_l[col]; wl[fj] = W_rel[col];
        wg[fj] = W_gate[col]; wo[fj] = W_root[col];
    }
#pragma unroll
    for (int fi = 0; fi < 2; fi++) {
#pragma unroll
        for (int r = 0; r < 4; r++) {
            int row = row0 + fi * 16 + g * 4 + r;
            if (row >= NN) continue;
            float py = 0.f, pc = 0.f, pr = 0.f;
#pragma unroll
            for (int fj = 0; fj < 4; fj++) {
                float v = fmaxf(acc[fi][fj][r] + bl[fj], 0.f);
                xout[(size_t)row * DD + wcol0 + fj * 16 + l15] = v;
                py = fmaf(v, wl[fj], py);
                pc = fmaf(v, wg[fj], pc);
                pr = fmaf(v, wo[fj], pr);
            }
#pragma unroll
            for (int off = 1; off < 16; off <<= 1) {
                py += __shfl_xor(py, off);
                pc += __shfl_xor(pc, off);
                pr += __shfl_xor(pr, off);
            }
            if (l15 == 0) {             // 4 atomics/address total: chain depth 4
                atomAddF(y + row, py);
                atomAddF(cvec + row, pc);
                atomAddF(rvec + row, pr);
            }
        }
    }
}

// ---------------- 6. gather y along CSR, score = tanh(.), sortable key ----
__global__ __launch_bounds__(256) void gather_score(
    const float* __restrict__ y, const float* __restrict__ r,
    const float* __restrict__ b_rel, const int* __restrict__ csr,
    const int* __restrict__ start,
    float* __restrict__ score, uint* __restrict__ key) {
    int gt   = blockIdx.x * 256 + threadIdx.x;
    int node = gt >> 6, lane = gt & 63;
    if (node >= NN) return;
    int s = start[node], e = start[node + 1];
    float acc = 0.f;
    for (int j = s + lane; j < e; j += 64) acc += y[csr[j]];
    for (int o = 32; o; o >>= 1) acc += __shfl_xor(acc, o);
    if (lane == 0) {
        float sc = tanhf(acc + b_rel[0] + r[node]);
        score[node] = sc;
        key[node]   = encodeF(sc);
    }
}

// ---------------- 7. radix select + max-logit + dense weights + denom -----
__global__ __launch_bounds__(1024) void radix_select(
    const uint* __restrict__ key, const float* __restrict__ score,
    const float* __restrict__ cvec,
    float* __restrict__ wsc, float* __restrict__ denom) {
    __shared__ uint  hist[256];
    __shared__ uint  ssum[256];
    __shared__ uint  sh_prefix, sh_need;
    __shared__ float wred[16];
    __shared__ uint  tick_s;
    const int t = threadIdx.x;
    uint prefix = 0, pmask = 0, need = KSEL;
    for (int shift = 24; shift >= 0; shift -= 8) {
        if (t < 256) hist[t] = 0;
        __syncthreads();
        for (int i = t; i < NN; i += 1024) {
            uint k = key[i];
            if ((k & pmask) == prefix) atomicAdd(&hist[(k >> shift) & 255], 1u);
        }
        __syncthreads();
        if (t < 256) ssum[t] = hist[t];
        __syncthreads();
        for (int off = 1; off < 256; off <<= 1) {   // parallel suffix sum
            uint add = 0;
            if (t < 256 && t + off < 256) add = ssum[t + off];
            __syncthreads();
            if (t < 256) ssum[t] += add;
            __syncthreads();
        }
        if (t < 256) {
            uint hi = ssum[t];
            uint lo = (t < 255) ? ssum[t + 1] : 0u;
            if (need <= hi && need > lo) {
                sh_prefix = prefix | ((uint)t << shift);
                sh_need   = need - lo;
            }
        }
        __syncthreads();
        prefix = sh_prefix;
        need   = sh_need;
        pmask |= (0xFFu << shift);
        __syncthreads();
    }
    const uint T      = prefix;
    const uint needEq = need;
    // ---- pass A: max logit over superset {key >= T} ----
    float v = -INFINITY;
    for (int i = t; i < NN; i += 1024)
        if (key[i] >= T) v = fmaxf(v, score[i] * cvec[i]);
    for (int o = 32; o; o >>= 1) v = fmaxf(v, __shfl_xor(v, o));
    if ((t & 63) == 0) wred[t >> 6] = v;
    if (t == 0) tick_s = 0;
    __syncthreads();
    float m = wred[0];
#pragma unroll
    for (int w = 1; w < 16; w++) m = fmaxf(m, wred[w]);
    __syncthreads();          // everyone has m before wred is reused
    // ---- pass B: dense weights + denom ----
    float dsum = 0.f;
    for (int i = t; i < NN; i += 1024) {
        uint k = key[i];
        bool selm = (k > T);
        if (k == T) selm = (atomicAdd(&tick_s, 1u) < needEq);
        float wv = 0.f;
        if (selm) {
            float s = score[i];
            float w = expf(s * cvec[i] - m);
            wv   = w * s;
            dsum += w;
        }
        wsc[i] = wv;
    }
    for (int o = 32; o; o >>= 1) dsum += __shfl_xor(dsum, o);
    if ((t & 63) == 0) wred[t >> 6] = dsum;
    __syncthreads();
    if (t == 0) {
        float d = 0.f;
#pragma unroll
        for (int w = 0; w < 16; w++) d += wred[w];
        denom[0] = d;
    }
}

// ---------------- 8. dense weighted row-sum -> per-block partials ---------
// NO global atomics: register acc -> LDS cross-wave reduce -> plain store.
__global__ __launch_bounds__(256) void reduce_rows(
    const float* __restrict__ x, const float* __restrict__ wsc,
    float* __restrict__ part) {
    __shared__ float red[3][DD];
    const int wave = threadIdx.x >> 6;
    const int lane = threadIdx.x & 63;
    const int row0 = (blockIdx.x * 4 + wave) * 16;
    const float* xp = x + lane * 4;
    float4 acc = make_float4(0.f, 0.f, 0.f, 0.f);
    if (row0 < NN) {
#pragma unroll
        for (int rb = 0; rb < 16; rb += 4) {
            int r0 = row0 + rb;
            float w0 = wsc[r0 + 0], w1 = wsc[r0 + 1];
            float w2 = wsc[r0 + 2], w3 = wsc[r0 + 3];
            float4 v0 = *(const float4*)(xp + (size_t)(r0 + 0) * DD);
            float4 v1 = *(const float4*)(xp + (size_t)(r0 + 1) * DD);
            float4 v2 = *(const float4*)(xp + (size_t)(r0 + 2) * DD);
            float4 v3 = *(const float4*)(xp + (size_t)(r0 + 3) * DD);
            acc.x = fmaf(w0, v0.x, fmaf(w1, v1.x, fmaf(w2, v2.x, fmaf(w3, v3.x, acc.x))));
            acc.y = fmaf(w0, v0.y, fmaf(w1, v1.y, fmaf(w2, v2.y, fmaf(w3, v3.y, acc.y))));
            acc.z = fmaf(w0, v0.z, fmaf(w1, v1.z, fmaf(w2, v2.z, fmaf(w3, v3.z, acc.z))));
            acc.w = fmaf(w0, v0.w, fmaf(w1, v1.w, fmaf(w2, v2.w, fmaf(w3, v3.w, acc.w))));
        }
    }
    if (wave > 0) *(float4*)&red[wave - 1][lane * 4] = acc;
    __syncthreads();
    if (wave == 0) {
#pragma unroll
        for (int w = 0; w < 3; w++) {
            float4 rv = *(float4*)&red[w][lane * 4];
            acc.x += rv.x; acc.y += rv.y; acc.z += rv.z; acc.w += rv.w;
        }
        *(float4*)(part + (size_t)blockIdx.x * DD + lane * 4) = acc;
    }
}

// ---------------- 9. finalize: sum partials, divide -----------------------
__global__ __launch_bounds__(256) void finalize(
    const float* __restrict__ part, const float* __restrict__ denom,
    float* __restrict__ out) {
    int i = threadIdx.x;
    float s = 0.f;
    for (int b = 0; b < NPART; b++) s += part[(size_t)b * DD + i];
    out[i] = s / denom[0];
}

extern "C" void kernel_launch(void* const* d_in, const int* in_sizes, int n_in,
                              void* d_out, int out_size, void* d_ws, size_t ws_size,
                              hipStream_t stream) {
    const float* h      = (const float*)d_in[0];
    const int*   ei     = (const int*)d_in[1];
    const float* W_l    = (const float*)d_in[2];
    const float* b_l    = (const float*)d_in[3];
    const float* W_r    = (const float*)d_in[4];
    const float* W_rel  = (const float*)d_in[5];
    const float* b_rel  = (const float*)d_in[6];
    const float* W_root = (const float*)d_in[7];
    const float* W_gate = (const float*)d_in[8];
    // b_gate (d_in[9]) cancels in softmax
    float* out = (float*)d_out;

    // ---- workspace layout ----
    ushort* Ab    = (ushort*)d_ws;                    // [NN][512] bf16: [mean|h]
    float*  xbuf  = (float*)(Ab + (size_t)NN * KK);   // N*D f32
    ushort* Wt    = (ushort*)(xbuf + (size_t)NN * DD);// [256][512] bf16
    int*    csr   = (int*)(Wt + (size_t)DD * KK);     // E
    int*    start = csr + NE;                         // N+1
    int*    cursor= start + NN + 1;                   // N
    float*  invdeg= (float*)(cursor + NN);            // N
    float*  score = invdeg + NN;                      // N
    uint*   key   = (uint*)(score + NN);              // N
    float*  wsc   = (float*)(key + NN);               // N (fully written)
    float*  denom = wsc + NN;                         // 1 (written directly)
    float*  part  = denom + 1;                        // NPART*D (fully written)
    // ---- zero-initialized tail (one small memset) ----
    int*    degi  = (int*)(part + (size_t)NPART * DD);// N
    float*  y     = (float*)(degi + NN);              // N
    float*  cbuf  = y + NN;                           // N
    float*  rbuf  = cbuf + NN;                        // N
    size_t zbytes = (size_t)((char*)(rbuf + NN) - (char*)degi);

    hipMemsetAsync(degi, 0, zbytes, stream);

    prep        <<<(QH + QW + NE + 255) / 256, 256, 0, stream>>>(h, W_l, W_r, ei,
                                                                 Ab, Wt, degi);
    scan_start  <<<1, 1024, 0, stream>>>(degi, start, cursor, invdeg);
    fill_csr    <<<(NE + 255) / 256, 256, 0, stream>>>(ei, cursor, csr);
    gather_mean <<<(NN + 3) / 4, 256, 0, stream>>>(Ab, csr, start, invdeg);
    gemm_x      <<<(NN + 31) / 32, 256, 0, stream>>>(Ab, Wt, b_l,
                                                     W_rel, W_gate, W_root,
                                                     xbuf, y, cbuf, rbuf);
    gather_score<<<(NN * 64 + 255) / 256, 256, 0, stream>>>(y, rbuf, b_rel, csr,
                                                            start, score, key);
    radix_select<<<1, 1024, 0, stream>>>(key, score, cbuf, wsc, denom);
    reduce_rows <<<NPART, 256, 0, stream>>>(xbuf, wsc, part);
    finalize    <<<1, 256, 0, stream>>>(part, denom, out);
    (void)n_in; (void)in_sizes; (void)out_size; (void)ws_size;
}

// Round 7
// 177.639 us; speedup vs baseline: 1.2903x; 1.0149x over previous
//
#include <hip/hip_runtime.h>
#include <math.h>

#define NN 10000
#define NE 320000
#define DD 256
#define KSEL 8000
#define KK 512
#define NPART 157          // reduce_rows grid

typedef unsigned int uint;
typedef unsigned short ushort;
typedef __attribute__((ext_vector_type(8))) short short8;   // 8 bf16 (4 VGPR)
typedef __attribute__((ext_vector_type(4))) float f32x4;
typedef __attribute__((ext_vector_type(4))) ushort us4;
typedef __attribute__((ext_vector_type(8))) ushort us8;

__device__ __forceinline__ void atomAddF(float* p, float v) {
    unsafeAtomicAdd(p, v);   // HW global_atomic_add_f32
}

__device__ __forceinline__ uint encodeF(float f) {
    uint u = __float_as_uint(f);
    return (u & 0x80000000u) ? ~u : (u | 0x80000000u);
}

__device__ __forceinline__ ushort f2bf(float f) {   // round-to-nearest-even
    uint u = __float_as_uint(f);
    u += 0x7FFFu + ((u >> 16) & 1u);
    return (ushort)(u >> 16);
}

// ---------------- 0. zero the atomic-accumulated buffers ------------------
// 160000 B = 10000 float4; 40 blocks x 256 threads, plain stores.
#define ZQUADS 10000
__global__ __launch_bounds__(256) void zero_bufs(float4* __restrict__ z) {
    int i = blockIdx.x * 256 + threadIdx.x;
    if (i < ZQUADS) z[i] = make_float4(0.f, 0.f, 0.f, 0.f);
}

// ---------------- 1. prep: cast_h + cast_W + count_deg (fused) ------------
#define QH (NN * 64)          // h cast quads
#define QW (KK * DD)          // W cast elems
__global__ __launch_bounds__(256) void prep(
    const float* __restrict__ h, const float* __restrict__ W_l,
    const float* __restrict__ W_r, const int* __restrict__ ei,
    ushort* __restrict__ Ab, ushort* __restrict__ Wt,
    int* __restrict__ degi) {
    int id = blockIdx.x * 256 + threadIdx.x;
    if (id < QH) {                       // ---- cast h -> A cols 256..511
        int node = id >> 6, seg = (id & 63) * 4;
        float4 v = *(const float4*)(h + (size_t)node * DD + seg);
        us4 o;
        o[0] = f2bf(v.x); o[1] = f2bf(v.y); o[2] = f2bf(v.z); o[3] = f2bf(v.w);
        *(us4*)(Ab + (size_t)node * KK + 256 + seg) = o;
    } else if (id < QH + QW) {           // ---- cast+transpose W -> Wt[256][512]
        int idx = id - QH;
        int k = idx >> 8, n = idx & 255;
        float v = (k < 256) ? W_l[(size_t)k * DD + n]
                            : W_r[(size_t)(k - 256) * DD + n];
        Wt[(size_t)n * KK + k] = f2bf(v);
    } else if (id < QH + QW + NE) {      // ---- degree histogram
        int e = id - QH - QW;
        atomicAdd(&degi[ei[NE + e]], 1);
    }
}

// ---------------- 2. single-block prefix scan -> start/cursor/invdeg ------
__global__ __launch_bounds__(1024) void scan_start(
    const int* __restrict__ degi, int* __restrict__ start,
    int* __restrict__ cursor, float* __restrict__ invdeg) {
    __shared__ int partial[1024];
    const int t  = threadIdx.x;
    const int CH = (NN + 1023) / 1024;   // 10
    const int base = t * CH;
    int sum = 0;
#pragma unroll
    for (int i = 0; i < CH; i++) {
        int idx = base + i;
        if (idx < NN) sum += degi[idx];
    }
    partial[t] = sum;
    __syncthreads();
    for (int off = 1; off < 1024; off <<= 1) {
        int add = (t >= off) ? partial[t - off] : 0;
        __syncthreads();
        partial[t] += add;
        __syncthreads();
    }
    int run = partial[t] - sum;
#pragma unroll
    for (int i = 0; i < CH; i++) {
        int idx = base + i;
        if (idx < NN) {
            start[idx]  = run;
            cursor[idx] = run;
            int d = degi[idx];
            invdeg[idx] = 1.0f / fmaxf((float)d, 1.0f);
            run += d;
        }
    }
    if (t == 1023) start[NN] = NE;
}

// ---------------- 3. fill CSR (group edges by dst) ------------------------
__global__ __launch_bounds__(256) void fill_csr(
    const int* __restrict__ ei, int* __restrict__ cursor,
    int* __restrict__ csr) {
    int e = blockIdx.x * 256 + threadIdx.x;
    if (e >= NE) return;
    int pos = atomicAdd(&cursor[ei[NE + e]], 1);
    csr[pos] = ei[e];
}

// ---------------- 4. gather-aggregate (bf16 reads) -> bf16 mean -----------
__global__ __launch_bounds__(256) void gather_mean(
    ushort* __restrict__ Ab, const int* __restrict__ csr,
    const int* __restrict__ start, const float* __restrict__ invdeg) {
    int node = blockIdx.x * 4 + (threadIdx.x >> 6);
    int lane = threadIdx.x & 63;
    if (node >= NN) return;
    int s = start[node], e = start[node + 1];
    const ushort* hb = Ab + 256 + lane * 4;            // h half of A
    float a0 = 0.f, a1 = 0.f, a2 = 0.f, a3 = 0.f;
    float b0 = 0.f, b1 = 0.f, b2 = 0.f, b3 = 0.f;
    int j = s;
    for (; j + 2 <= e; j += 2) {
        int s0 = csr[j], s1 = csr[j + 1];
        uint2 v0 = *(const uint2*)(hb + (size_t)s0 * KK);
        uint2 v1 = *(const uint2*)(hb + (size_t)s1 * KK);
        a0 += __uint_as_float(v0.x << 16);
        a1 += __uint_as_float(v0.x & 0xFFFF0000u);
        a2 += __uint_as_float(v0.y << 16);
        a3 += __uint_as_float(v0.y & 0xFFFF0000u);
        b0 += __uint_as_float(v1.x << 16);
        b1 += __uint_as_float(v1.x & 0xFFFF0000u);
        b2 += __uint_as_float(v1.y << 16);
        b3 += __uint_as_float(v1.y & 0xFFFF0000u);
    }
    for (; j < e; j++) {
        uint2 v0 = *(const uint2*)(hb + (size_t)csr[j] * KK);
        a0 += __uint_as_float(v0.x << 16);
        a1 += __uint_as_float(v0.x & 0xFFFF0000u);
        a2 += __uint_as_float(v0.y << 16);
        a3 += __uint_as_float(v0.y & 0xFFFF0000u);
    }
    float id = invdeg[node];
    us4 m;
    m[0] = f2bf((a0 + b0) * id);
    m[1] = f2bf((a1 + b1) * id);
    m[2] = f2bf((a2 + b2) * id);
    m[3] = f2bf((a3 + b3) * id);
    *(us4*)(Ab + (size_t)node * KK + lane * 4) = m;    // mean half of A
}

// ---------------- 5. MFMA GEMM: x = relu(A@Wt^T + b_l), fused y/c/r -------
__global__ __launch_bounds__(256) void gemm_x(
    const ushort* __restrict__ Ab, const ushort* __restrict__ Wt,
    const float* __restrict__ b_l,
    const float* __restrict__ W_rel, const float* __restrict__ W_gate,
    const float* __restrict__ W_root,
    float* __restrict__ xout, float* __restrict__ y,
    float* __restrict__ cvec, float* __restrict__ rvec) {
    __shared__ ushort Asm[2][32][40];    // +8 pad: 2-way banks max
    __shared__ ushort Bsm[2][256][40];
    const int t    = threadIdx.x;
    const int row0 = blockIdx.x * 32;
    const int wid  = t >> 6, lane = t & 63;
    const int l15  = lane & 15, g = lane >> 4;

    f32x4 acc[2][4];
#pragma unroll
    for (int fi = 0; fi < 2; fi++)
#pragma unroll
        for (int fj = 0; fj < 4; fj++) acc[fi][fj] = (f32x4)0.f;

    const int  arow = t >> 3, akseg = (t & 7) * 4;
    const bool aok  = (row0 + arow) < NN;
    const ushort* aptr = Ab + (size_t)(row0 + arow) * KK + akseg;
    const ushort* bptr = Wt + (size_t)t * KK;

    us4 areg = {0, 0, 0, 0};
    us8 breg[4];
    if (aok) areg = *(const us4*)(aptr);
#pragma unroll
    for (int jj = 0; jj < 4; jj++) breg[jj] = *(const us8*)(bptr + jj * 8);
    *(us4*)&Asm[0][arow][akseg] = areg;
#pragma unroll
    for (int jj = 0; jj < 4; jj++) *(us8*)&Bsm[0][t][jj * 8] = breg[jj];
    __syncthreads();

    for (int ks = 0; ks < 16; ++ks) {
        const int cur = ks & 1;
        if (ks < 15) {
            const int k0 = (ks + 1) * 32;
            if (aok) areg = *(const us4*)(aptr + k0);
#pragma unroll
            for (int jj = 0; jj < 4; jj++) breg[jj] = *(const us8*)(bptr + k0 + jj * 8);
        }
        short8 af0 = *(const short8*)&Asm[cur][l15][g * 8];
        short8 af1 = *(const short8*)&Asm[cur][16 + l15][g * 8];
#pragma unroll
        for (int fj = 0; fj < 4; fj++) {
            short8 bf = *(const short8*)&Bsm[cur][wid * 64 + fj * 16 + l15][g * 8];
            acc[0][fj] = __builtin_amdgcn_mfma_f32_16x16x32_bf16(af0, bf, acc[0][fj], 0, 0, 0);
            acc[1][fj] = __builtin_amdgcn_mfma_f32_16x16x32_bf16(af1, bf, acc[1][fj], 0, 0, 0);
        }
        if (ks < 15) {
            const int nb = cur ^ 1;
            *(us4*)&Asm[nb][arow][akseg] = areg;
#pragma unroll
            for (int jj = 0; jj < 4; jj++) *(us8*)&Bsm[nb][t][jj * 8] = breg[jj];
        }
        __syncthreads();
    }

    const int wcol0 = wid * 64;
    float bl[4], wl[4], wg[4], wo[4];
#pragma unroll
    for (int fj = 0; fj < 4; fj++) {
        int col = wcol0 + fj * 16 + l15;
        bl[fj] = b_l[col]; wl[fj] = W_rel[col];
        wg[fj] = W_gate[col]; wo[fj] = W_root[col];
    }
#pragma unroll
    for (int fi = 0; fi < 2; fi++) {
#pragma unroll
        for (int r = 0; r < 4; r++) {
            int row = row0 + fi * 16 + g * 4 + r;
            if (row >= NN) continue;
            float py = 0.f, pc = 0.f, pr = 0.f;
#pragma unroll
            for (int fj = 0; fj < 4; fj++) {
                float v = fmaxf(acc[fi][fj][r] + bl[fj], 0.f);
                xout[(size_t)row * DD + wcol0 + fj * 16 + l15] = v;
                py = fmaf(v, wl[fj], py);
                pc = fmaf(v, wg[fj], pc);
                pr = fmaf(v, wo[fj], pr);
            }
#pragma unroll
            for (int off = 1; off < 16; off <<= 1) {
                py += __shfl_xor(py, off);
                pc += __shfl_xor(pc, off);
                pr += __shfl_xor(pr, off);
            }
            if (l15 == 0) {             // 4 atomics/address total: chain depth 4
                atomAddF(y + row, py);
                atomAddF(cvec + row, pc);
                atomAddF(rvec + row, pr);
            }
        }
    }
}

// ---------------- 6. gather y along CSR, score = tanh(.), sortable key ----
__global__ __launch_bounds__(256) void gather_score(
    const float* __restrict__ y, const float* __restrict__ r,
    const float* __restrict__ b_rel, const int* __restrict__ csr,
    const int* __restrict__ start,
    float* __restrict__ score, uint* __restrict__ key) {
    int gt   = blockIdx.x * 256 + threadIdx.x;
    int node = gt >> 6, lane = gt & 63;
    if (node >= NN) return;
    int s = start[node], e = start[node + 1];
    float acc = 0.f;
    for (int j = s + lane; j < e; j += 64) acc += y[csr[j]];
    for (int o = 32; o; o >>= 1) acc += __shfl_xor(acc, o);
    if (lane == 0) {
        float sc = tanhf(acc + b_rel[0] + r[node]);
        score[node] = sc;
        key[node]   = encodeF(sc);
    }
}

// ---------------- 7. radix select + max-logit + dense weights + denom -----
__global__ __launch_bounds__(1024) void radix_select(
    const uint* __restrict__ key, const float* __restrict__ score,
    const float* __restrict__ cvec,
    float* __restrict__ wsc, float* __restrict__ denom) {
    __shared__ uint  hist[256];
    __shared__ uint  ssum[256];
    __shared__ uint  sh_prefix, sh_need;
    __shared__ float wred[16];
    __shared__ uint  tick_s;
    const int t = threadIdx.x;
    uint prefix = 0, pmask = 0, need = KSEL;
    for (int shift = 24; shift >= 0; shift -= 8) {
        if (t < 256) hist[t] = 0;
        __syncthreads();
        for (int i = t; i < NN; i += 1024) {
            uint k = key[i];
            if ((k & pmask) == prefix) atomicAdd(&hist[(k >> shift) & 255], 1u);
        }
        __syncthreads();
        if (t < 256) ssum[t] = hist[t];
        __syncthreads();
        for (int off = 1; off < 256; off <<= 1) {   // parallel suffix sum
            uint add = 0;
            if (t < 256 && t + off < 256) add = ssum[t + off];
            __syncthreads();
            if (t < 256) ssum[t] += add;
            __syncthreads();
        }
        if (t < 256) {
            uint hi = ssum[t];
            uint lo = (t < 255) ? ssum[t + 1] : 0u;
            if (need <= hi && need > lo) {
                sh_prefix = prefix | ((uint)t << shift);
                sh_need   = need - lo;
            }
        }
        __syncthreads();
        prefix = sh_prefix;
        need   = sh_need;
        pmask |= (0xFFu << shift);
        __syncthreads();
    }
    const uint T      = prefix;
    const uint needEq = need;
    // ---- pass A: max logit over superset {key >= T} ----
    float v = -INFINITY;
    for (int i = t; i < NN; i += 1024)
        if (key[i] >= T) v = fmaxf(v, score[i] * cvec[i]);
    for (int o = 32; o; o >>= 1) v = fmaxf(v, __shfl_xor(v, o));
    if ((t & 63) == 0) wred[t >> 6] = v;
    if (t == 0) tick_s = 0;
    __syncthreads();
    float m = wred[0];
#pragma unroll
    for (int w = 1; w < 16; w++) m = fmaxf(m, wred[w]);
    __syncthreads();          // everyone has m before wred is reused
    // ---- pass B: dense weights + denom ----
    float dsum = 0.f;
    for (int i = t; i < NN; i += 1024) {
        uint k = key[i];
        bool selm = (k > T);
        if (k == T) selm = (atomicAdd(&tick_s, 1u) < needEq);
        float wv = 0.f;
        if (selm) {
            float s = score[i];
            float w = expf(s * cvec[i] - m);
            wv   = w * s;
            dsum += w;
        }
        wsc[i] = wv;
    }
    for (int o = 32; o; o >>= 1) dsum += __shfl_xor(dsum, o);
    if ((t & 63) == 0) wred[t >> 6] = dsum;
    __syncthreads();
    if (t == 0) {
        float d = 0.f;
#pragma unroll
        for (int w = 0; w < 16; w++) d += wred[w];
        denom[0] = d;
    }
}

// ---------------- 8. dense weighted row-sum -> per-block partials ---------
// NO global atomics: register acc -> LDS cross-wave reduce -> plain store.
__global__ __launch_bounds__(256) void reduce_rows(
    const float* __restrict__ x, const float* __restrict__ wsc,
    float* __restrict__ part) {
    __shared__ float red[3][DD];
    const int wave = threadIdx.x >> 6;
    const int lane = threadIdx.x & 63;
    const int row0 = (blockIdx.x * 4 + wave) * 16;
    const float* xp = x + lane * 4;
    float4 acc = make_float4(0.f, 0.f, 0.f, 0.f);
    if (row0 < NN) {
#pragma unroll
        for (int rb = 0; rb < 16; rb += 4) {
            int r0 = row0 + rb;
            float w0 = wsc[r0 + 0], w1 = wsc[r0 + 1];
            float w2 = wsc[r0 + 2], w3 = wsc[r0 + 3];
            float4 v0 = *(const float4*)(xp + (size_t)(r0 + 0) * DD);
            float4 v1 = *(const float4*)(xp + (size_t)(r0 + 1) * DD);
            float4 v2 = *(const float4*)(xp + (size_t)(r0 + 2) * DD);
            float4 v3 = *(const float4*)(xp + (size_t)(r0 + 3) * DD);
            acc.x = fmaf(w0, v0.x, fmaf(w1, v1.x, fmaf(w2, v2.x, fmaf(w3, v3.x, acc.x))));
            acc.y = fmaf(w0, v0.y, fmaf(w1, v1.y, fmaf(w2, v2.y, fmaf(w3, v3.y, acc.y))));
            acc.z = fmaf(w0, v0.z, fmaf(w1, v1.z, fmaf(w2, v2.z, fmaf(w3, v3.z, acc.z))));
            acc.w = fmaf(w0, v0.w, fmaf(w1, v1.w, fmaf(w2, v2.w, fmaf(w3, v3.w, acc.w))));
        }
    }
    if (wave > 0) *(float4*)&red[wave - 1][lane * 4] = acc;
    __syncthreads();
    if (wave == 0) {
#pragma unroll
        for (int w = 0; w < 3; w++) {
            float4 rv = *(float4*)&red[w][lane * 4];
            acc.x += rv.x; acc.y += rv.y; acc.z += rv.z; acc.w += rv.w;
        }
        *(float4*)(part + (size_t)blockIdx.x * DD + lane * 4) = acc;
    }
}

// ---------------- 9. finalize: sum partials, divide -----------------------
__global__ __launch_bounds__(256) void finalize(
    const float* __restrict__ part, const float* __restrict__ denom,
    float* __restrict__ out) {
    int i = threadIdx.x;
    float s = 0.f;
    for (int b = 0; b < NPART; b++) s += part[(size_t)b * DD + i];
    out[i] = s / denom[0];
}

extern "C" void kernel_launch(void* const* d_in, const int* in_sizes, int n_in,
                              void* d_out, int out_size, void* d_ws, size_t ws_size,
                              hipStream_t stream) {
    const float* h      = (const float*)d_in[0];
    const int*   ei     = (const int*)d_in[1];
    const float* W_l    = (const float*)d_in[2];
    const float* b_l    = (const float*)d_in[3];
    const float* W_r    = (const float*)d_in[4];
    const float* W_rel  = (const float*)d_in[5];
    const float* b_rel  = (const float*)d_in[6];
    const float* W_root = (const float*)d_in[7];
    const float* W_gate = (const float*)d_in[8];
    // b_gate (d_in[9]) cancels in softmax
    float* out = (float*)d_out;

    // ---- workspace layout, every array 64B-aligned ----
    char* p = (char*)d_ws;
    auto alloc = [&p](size_t bytes) {
        char* q = p;
        p += (bytes + 63) & ~(size_t)63;
        return q;
    };
    ushort* Ab    = (ushort*)alloc((size_t)NN * KK * 2);      // [NN][512] bf16
    float*  xbuf  = (float*) alloc((size_t)NN * DD * 4);      // N*D f32
    ushort* Wt    = (ushort*)alloc((size_t)DD * KK * 2);      // [256][512] bf16
    int*    csr   = (int*)   alloc((size_t)NE * 4);           // E
    int*    start = (int*)   alloc((size_t)(NN + 1) * 4);     // N+1
    int*    cursor= (int*)   alloc((size_t)NN * 4);           // N
    float*  invdeg= (float*) alloc((size_t)NN * 4);           // N
    float*  score = (float*) alloc((size_t)NN * 4);           // N
    uint*   key   = (uint*)  alloc((size_t)NN * 4);           // N
    float*  wsc   = (float*) alloc((size_t)NN * 4);           // N (fully written)
    float*  denom = (float*) alloc(64);                       // 1
    float*  part  = (float*) alloc((size_t)NPART * DD * 4);   // fully written
    // ---- zero-initialized region (contiguous, 160000 B = 10000 float4) ----
    int*    degi  = (int*)   alloc((size_t)NN * 4);           // N
    float*  y     = (float*) alloc((size_t)NN * 4);           // N
    float*  cbuf  = (float*) alloc((size_t)NN * 4);           // N
    float*  rbuf  = (float*) alloc((size_t)NN * 4);           // N

    zero_bufs   <<<(ZQUADS + 255) / 256, 256, 0, stream>>>((float4*)degi);
    prep        <<<(QH + QW + NE + 255) / 256, 256, 0, stream>>>(h, W_l, W_r, ei,
                                                                 Ab, Wt, degi);
    scan_start  <<<1, 1024, 0, stream>>>(degi, start, cursor, invdeg);
    fill_csr    <<<(NE + 255) / 256, 256, 0, stream>>>(ei, cursor, csr);
    gather_mean <<<(NN + 3) / 4, 256, 0, stream>>>(Ab, csr, start, invdeg);
    gemm_x      <<<(NN + 31) / 32, 256, 0, stream>>>(Ab, Wt, b_l,
                                                     W_rel, W_gate, W_root,
                                                     xbuf, y, cbuf, rbuf);
    gather_score<<<(NN * 64 + 255) / 256, 256, 0, stream>>>(y, rbuf, b_rel, csr,
                                                            start, score, key);
    radix_select<<<1, 1024, 0, stream>>>(key, score, cbuf, wsc, denom);
    reduce_rows <<<NPART, 256, 0, stream>>>(xbuf, wsc, part);
    finalize    <<<1, 256, 0, stream>>>(part, denom, out);
    (void)n_in; (void)in_sizes; (void)out_size; (void)ws_size;
}